// Round 3
// baseline (176.705 us; speedup 1.0000x reference)
//
#include <hip/hip_runtime.h>
#include <stdint.h>

#define NB   16
#define CD   256
#define HW   1024
#define NQ   16384
#define KCN  8192

typedef unsigned long long u64;
typedef unsigned short     u16;
using f32x4  = __attribute__((ext_vector_type(4))) float;
using bf16x8 = __attribute__((ext_vector_type(8))) __bf16;

// ---------------- workspace layout (~16.9 MB) ----------------
#define ZTB_OFF  0            // u16  [NQ][CD]    8 MB  (z transposed, bf16)
#define EMBB_OFF 8388608      // u16  [KCN][CD]   4 MB  (emb, bf16)
#define EH_OFF   12582912     // f32  [KCN]      32 KB  (||e||^2/2 + 1024)
#define CAND_OFF 12615680     // u64  [NQ][32]    4 MB  (8 splits x 2 halves x top-2)

static __device__ __forceinline__ void gl_lds16(const void* g, void* l) {
  __builtin_amdgcn_global_load_lds(
      (const __attribute__((address_space(1))) void*)g,
      (__attribute__((address_space(3))) void*)l, 16, 0, 0);
}

static __device__ __forceinline__ unsigned bf16r(float x) {  // RNE fp32->bf16 bits
  unsigned u = __float_as_uint(x);
  return (u + 0x7fffu + ((u >> 16) & 1u)) >> 16;
}

static __device__ __forceinline__ u64 umin64(u64 a, u64 b) { return a < b ? a : b; }
static __device__ __forceinline__ u64 umax64(u64 a, u64 b) { return a < b ? b : a; }

// ---------------- kernel 1: merged prep (unchanged) ----------------
__global__ __launch_bounds__(256) void k_prep(const float* __restrict__ z,
                                              const float* __restrict__ emb,
                                              u16* __restrict__ zTb,
                                              u16* __restrict__ embB,
                                              float* __restrict__ eH) {
  const int bx = (int)blockIdx.x;
  if (bx < 1024) {
    __shared__ float tile[64][65];
    const int b   = bx >> 6;
    const int hwT = (bx >> 2) & 15;
    const int cT  = bx & 3;
    const int tx  = threadIdx.x & 63;
    const int ty  = threadIdx.x >> 6;
    const float* src = z + (size_t)(b * CD + cT * 64) * HW + hwT * 64;
#pragma unroll
    for (int i = 0; i < 16; ++i) {
      const int c_l = ty + 4 * i;
      tile[c_l][tx] = src[(size_t)c_l * HW + tx];
    }
    __syncthreads();
    const size_t dbase = (size_t)(b * HW + hwT * 64) * CD + cT * 64;
#pragma unroll
    for (int i = 0; i < 16; ++i) {
      const int hw_l = ty + 4 * i;
      zTb[dbase + (size_t)hw_l * CD + tx] = (u16)bf16r(tile[tx][hw_l]);
    }
  } else {
    const int wave = (bx - 1024) * 4 + ((int)threadIdx.x >> 6);  // 0..1023
    const int lane = threadIdx.x & 63;
#pragma unroll
    for (int it = 0; it < 8; ++it) {
      const int row = wave * 8 + it;
      const float4 v = *(const float4*)(emb + (size_t)row * CD + lane * 4);
      uint2 pk;
      pk.x = bf16r(v.x) | (bf16r(v.y) << 16);
      pk.y = bf16r(v.z) | (bf16r(v.w) << 16);
      *(uint2*)(embB + (size_t)row * CD + lane * 4) = pk;
      float s = v.x * v.x + v.y * v.y + v.z * v.z + v.w * v.w;
#pragma unroll
      for (int off = 32; off; off >>= 1) s += __shfl_xor(s, off, 64);
      if (lane == 0) eH[row] = 0.5f * s + 1024.0f;
    }
  }
}

// ---------------- kernel 2: R12 — Q=64/wave in regs, N=32/wave, 4x reuse ----------
// R11 post-mortem: per-wave B-LDS-read per 64k-interval was 16KB (Q=32,N=128) ==
// R9's A+B traffic -> LDS port ~3x oversubscribed vs MFMA, MfmaUtil pinned ~30%.
// LDS bytes/FLOP for B = 1/Q_per_wave. R12: waves = 2 q-halves x 2 n-halves; each
// wave: Q=64 (A resident, Af[4][2][4] = 128 VGPR), N=32 per chunk. Chunks: 64
// n-rows x 128 k = 16KB, ring 4 (64KB LDS), 4 gl_lds16/thread/stage. Per chunk
// per wave: 8 ds_read_b128 (8KB) feeding 32 MFMA -> LDS ~37% of MFMA time.
// Counted vmcnt ledger (4-DMA chunks, 2-load eh, eh double-buffered 1 nt ahead;
// queue entering each iter: [c0(4),ehA(2),c1(4),c2(4),ehB(2)]=16):
//   WAITV(12)->c0 | bar | STAGE c3 | MFMA(r0,kc0)
//   WAITV(10)->c1 (drains ehA too) | bar | STAGE c4, ehA' | MFMA(r1,kc1) | EPI(ntA)
//   WAITV(12)->c2 | bar | STAGE c5 | MFMA(r2,kc0)
//   WAITV(10)->c3 | bar | STAGE c6, ehB' | MFMA(r3,kc1) | EPI(ntB)
// Buckets identical to R9: (split, n-half) top-2, id = nc*2+j (5 bits, &~31u),
// 16-lane butterfly, same cand layout; k_prep/k_pick_out untouched.

#define WAITV(N) asm volatile("s_waitcnt vmcnt(" #N ")" ::: "memory")
#define MEMFENCE() asm volatile("" ::: "memory")

__global__ __launch_bounds__(256, 2) void k_argmin(const u16* __restrict__ zTb,
                                                   const u16* __restrict__ embB,
                                                   const float* __restrict__ eH,
                                                   u64* __restrict__ cand) {
  __shared__ __align__(16) u16 Bs[4][64 * 128];   // 16 KB per ring slot

  const int tid  = (int)threadIdx.x;
  const int w    = tid >> 6;
  const int lane = tid & 63;
  const int l15  = lane & 15, quad = lane >> 4;
  const int q0    = (int)(blockIdx.x >> 3) * 128;
  const int split = (int)(blockIdx.x & 7);
  const int wq0 = (w & 1) * 64;    // q-half
  const int nh  = w >> 1;          // n-half (bucket)

  // ---- A fragments resident in registers (128 VGPR):
  // Af[i][kcH][ks][lane(quad,l15)] = A[q0+wq0+i*16+l15][kcH*128+ks*32+quad*8 ..+7]
  bf16x8 Af[4][2][4];
  {
    const char* aB = (const char*)zTb + (size_t)(q0 + wq0 + l15) * 512 + quad * 16;
#pragma unroll
    for (int i = 0; i < 4; ++i)
#pragma unroll
      for (int kc = 0; kc < 2; ++kc)
#pragma unroll
        for (int ks = 0; ks < 4; ++ks)
          Af[i][kc][ks] = *(const bf16x8*)(aB + i * 8192 + kc * 256 + ks * 64);
  }
  MEMFENCE();   // pin: A loads issue before staging DMAs (oldest in vmcnt queue)

  // ---- B staging: thread t, DMA u=0..3: LDS byte u*4096 + t*16
  // -> row = u*16 + (t>>4), slot = t&15; stored granule = slot ^ (row&7)
  // (pre-swizzled global source, linear LDS dest). Chunk = 64 rows x 128 k.
  const char* bS = (const char*)embB + (size_t)split * 524288
                 + (size_t)(tid >> 4) * 512
                 + (size_t)(((tid & 15) ^ ((tid >> 4) & 7)) * 16);
  const int ldsW = tid * 16;

#define STAGE(RING, SRCOFF)                                                    \
  do {                                                                         \
    const char* _s = bP + (SRCOFF);                                            \
    char* _d = (char*)Bs[RING] + ldsW;                                         \
    gl_lds16(_s,         _d);                                                  \
    gl_lds16(_s + 8192,  _d + 4096);                                           \
    gl_lds16(_s + 16384, _d + 8192);                                           \
    gl_lds16(_s + 24576, _d + 12288);                                          \
    MEMFENCE();                                                                \
  } while (0)

  // frag reads: row = nh*32 + j*16 + l15 (row&7 = l15&7), granule g = ks*4+quad
  // at slot g ^ (l15&7); 16-lane group hits 8 distinct 16B slots = 2-way (free)
  const int bRow = (nh * 32 + l15) * 256;
  const int gx   = l15 & 7;

#define MFMA_INT(RING, KCH)                                                    \
  do {                                                                         \
    const char* _b = (const char*)Bs[RING] + bRow;                             \
    __builtin_amdgcn_s_setprio(1);                                             \
    _Pragma("unroll")                                                          \
    for (int ks = 0; ks < 4; ++ks) {                                           \
      const int _o = ((ks * 4 + quad) ^ gx) * 16;                              \
      const bf16x8 bf0 = *(const bf16x8*)(_b + _o);                            \
      const bf16x8 bf1 = *(const bf16x8*)(_b + 4096 + _o);                     \
      _Pragma("unroll")                                                        \
      for (int i = 0; i < 4; ++i)                                              \
        acc[i][0] = __builtin_amdgcn_mfma_f32_16x16x32_bf16(Af[i][KCH][ks],    \
                                                            bf0, acc[i][0],    \
                                                            0, 0, 0);          \
      _Pragma("unroll")                                                        \
      for (int i = 0; i < 4; ++i)                                              \
        acc[i][1] = __builtin_amdgcn_mfma_f32_16x16x32_bf16(Af[i][KCH][ks],    \
                                                            bf1, acc[i][1],    \
                                                            0, 0, 0);          \
    }                                                                          \
    __builtin_amdgcn_s_setprio(0);                                             \
  } while (0)

#define ACCZERO()                                                              \
  do {                                                                         \
    _Pragma("unroll")                                                          \
    for (int i = 0; i < 4; ++i) {                                              \
      acc[i][0] = f32x4{0.f, 0.f, 0.f, 0.f};                                   \
      acc[i][1] = f32x4{0.f, 0.f, 0.f, 0.f};                                   \
    }                                                                          \
  } while (0)

#define EPILOGUE(NC, EH0, EH1)                                                 \
  do {                                                                         \
    _Pragma("unroll")                                                          \
    for (int i = 0; i < 4; ++i)                                                \
      _Pragma("unroll")                                                        \
      for (int r = 0; r < 4; ++r) {                                            \
        const int s = i * 4 + r;                                               \
        const unsigned kb0 = (__float_as_uint((EH0) - acc[i][0][r]) & ~31u)    \
                             | (unsigned)((NC) * 2 + 0);                       \
        const unsigned kb1 = (__float_as_uint((EH1) - acc[i][1][r]) & ~31u)    \
                             | (unsigned)((NC) * 2 + 1);                       \
        const float k0 = __uint_as_float(kb0), k1 = __uint_as_float(kb1);      \
        const float lo = fminf(k0, k1), hi = fmaxf(k0, k1);                    \
        b2[s] = fminf(fmaxf(lo, b1[s]), fminf(hi, b2[s]));                     \
        b1[s] = fminf(lo, b1[s]);                                              \
      }                                                                        \
  } while (0)

  f32x4 acc[4][2];
  float b1[16], b2[16];
  const float FMAX = __uint_as_float(0x7F7FFFFFu);
#pragma unroll
  for (int s = 0; s < 16; ++s) { b1[s] = FMAX; b2[s] = FMAX; }

  const float* ehP = eH + split * 1024 + nh * 32 + l15;
  float ehA[2], ehB[2], ehAn[2], ehBn[2];

  // ---- prologue: queue = [c0(4), ehA(2), c1(4), c2(4), ehB(2)] = 16
  const char* bP = bS;
  STAGE(0, 0);                                   // c0 (nc0, kc0)
  ehA[0] = ehP[0];  ehA[1] = ehP[16];  MEMFENCE();
  STAGE(1, 256);                                 // c1 (nc0, kc1)
  STAGE(2, 32768);                               // c2 (nc1, kc0)
  ehB[0] = ehP[64]; ehB[1] = ehP[80]; MEMFENCE();
  const float* ehPn = ehP + 128;                 // nc=2 base for prefetch

  // ---- main loop: ntp = 0..6 handles nt 2ntp, 2ntp+1 (chunks 4ntp .. 4ntp+3)
  for (int ntp = 0; ntp < 7; ++ntp) {
    const int nca = 2 * ntp, ncb = 2 * ntp + 1;

    ACCZERO();
    WAITV(12); __builtin_amdgcn_s_barrier(); MEMFENCE();   // c0 done
    STAGE(3, 33024);                            // c3 (ncb, kc1)
    MFMA_INT(0, 0);

    WAITV(10); __builtin_amdgcn_s_barrier(); MEMFENCE();   // c1 done (+ehA)
    STAGE(0, 65536);                            // c4 = next iter c0
    ehAn[0] = ehPn[0]; ehAn[1] = ehPn[16]; MEMFENCE();
    MFMA_INT(1, 1);
    EPILOGUE(nca, ehA[0], ehA[1]);

    ACCZERO();
    WAITV(12); __builtin_amdgcn_s_barrier(); MEMFENCE();   // c2 done
    STAGE(1, 65792);                            // c5 = next iter c1
    MFMA_INT(2, 0);

    WAITV(10); __builtin_amdgcn_s_barrier(); MEMFENCE();   // c3 done (+ehB)
    STAGE(2, 98304);                            // c6 = next iter c2
    ehBn[0] = ehPn[64]; ehBn[1] = ehPn[80]; MEMFENCE();
    MFMA_INT(3, 1);
    EPILOGUE(ncb, ehB[0], ehB[1]);

    ehA[0] = ehAn[0]; ehA[1] = ehAn[1];
    ehB[0] = ehBn[0]; ehB[1] = ehBn[1];
    bP += 65536;
    ehPn += 128;
  }

  // ---- peeled ntp = 7 (chunks 28..31; queue [c28,ehA,c29,c30,ehB] = 16)
  {
    ACCZERO();
    WAITV(12); __builtin_amdgcn_s_barrier(); MEMFENCE();   // c28 done
    STAGE(3, 33024);                            // c31
    MFMA_INT(0, 0);

    WAITV(10); __builtin_amdgcn_s_barrier(); MEMFENCE();   // c29 done (+ehA)
    MFMA_INT(1, 1);
    EPILOGUE(14, ehA[0], ehA[1]);

    ACCZERO();
    WAITV(6); __builtin_amdgcn_s_barrier(); MEMFENCE();    // c30 done
    MFMA_INT(2, 0);

    WAITV(0); __builtin_amdgcn_s_barrier(); MEMFENCE();    // c31 done
    MFMA_INT(3, 1);
    EPILOGUE(15, ehB[0], ehB[1]);
  }
#undef STAGE
#undef MFMA_INT
#undef ACCZERO
#undef EPILOGUE

  // ---- per-wave: u64 butterfly top-2 merge over 16-lane groups, write cand
#pragma unroll
  for (int s = 0; s < 16; ++s) {
    u64 x1 = ((u64)__float_as_uint(b1[s]) << 32) | (unsigned)l15;
    u64 x2 = ((u64)__float_as_uint(b2[s]) << 32) | (unsigned)l15;
#pragma unroll
    for (int off = 1; off < 16; off <<= 1) {
      const u64 o1 = __shfl_xor(x1, off, 64);
      const u64 o2 = __shfl_xor(x2, off, 64);
      const u64 lo = umin64(x1, o1);
      const u64 hi = umax64(x1, o1);
      x1 = lo;
      x2 = umin64(hi, umin64(x2, o2));
    }
    if (l15 == 0) {
      const int i = s >> 2, r = s & 3;
      const int q = q0 + wq0 + i * 16 + quad * 4 + r;
      const unsigned kb1 = (unsigned)(x1 >> 32), kb2 = (unsigned)(x2 >> 32);
      // id = nc*2 + j (5 bits): n = split*1024 + nc*64 + nh*32 + j*16 + col
      const int id1 = (int)(kb1 & 31u), id2 = (int)(kb2 & 31u);
      const int n1 = split * 1024 + (id1 >> 1) * 64 + nh * 32
                     + (id1 & 1) * 16 + (int)(x1 & 15);
      const int n2 = split * 1024 + (id2 >> 1) * 64 + nh * 32
                     + (id2 & 1) * 16 + (int)(x2 & 15);
      cand[(size_t)q * 32 + split * 4 + nh * 2 + 0] = ((u64)kb1 << 32) | (unsigned)n1;
      cand[(size_t)q * 32 + split * 4 + nh * 2 + 1] = ((u64)kb2 << 32) | (unsigned)n2;
    }
  }
}

// ---------------- kernel 3: select + fp64 rescore (native z) + output (unchanged) ----
__global__ __launch_bounds__(256) void k_pick_out(const float* __restrict__ z,
                                                  const float* __restrict__ emb,
                                                  const u64* __restrict__ cand,
                                                  float* __restrict__ out) {
  __shared__ float zs[16][257];
  __shared__ float tile[16][257];
  const int t    = (int)threadIdx.x;
  const int lane = t & 63;
  const int wv   = t >> 6;
  const int sub  = lane >> 4;
  const int l15  = lane & 15;
  const int q0b  = (int)blockIdx.x * 16;
  const int b    = q0b >> 10, hw0 = q0b & 1023;
  const int q    = q0b + wv * 4 + sub;
  const int hwl  = wv * 4 + sub;

  // ---- phase 0: stage z slice (thread t = channel)
  {
    const float* zp = z + ((size_t)(b * CD + t)) * HW + hw0;
    const float4 a0 = *(const float4*)(zp + 0);
    const float4 a1 = *(const float4*)(zp + 4);
    const float4 a2 = *(const float4*)(zp + 8);
    const float4 a3 = *(const float4*)(zp + 12);
    zs[0][t] = a0.x;  zs[1][t] = a0.y;  zs[2][t] = a0.z;  zs[3][t] = a0.w;
    zs[4][t] = a1.x;  zs[5][t] = a1.y;  zs[6][t] = a1.z;  zs[7][t] = a1.w;
    zs[8][t] = a2.x;  zs[9][t] = a2.y;  zs[10][t] = a2.z; zs[11][t] = a2.w;
    zs[12][t] = a3.x; zs[13][t] = a3.y; zs[14][t] = a3.z; zs[15][t] = a3.w;
  }
  __syncthreads();

  // ---- phase 1: top-4-of-32 select (butterfly merge of sorted-2 lists)
  const u64* cp = cand + (size_t)q * 32 + l15 * 2;
  const u64 v0 = cp[0], v1 = cp[1];
  u64 s0 = umin64(v0, v1), s1 = umax64(v0, v1), s2 = ~0ull, s3 = ~0ull;
#pragma unroll
  for (int off = 1; off < 16; off <<= 1) {
    const u64 b0 = __shfl_xor(s0, off, 64);
    const u64 b1 = __shfl_xor(s1, off, 64);
    const u64 b2 = __shfl_xor(s2, off, 64);
    const u64 b3 = __shfl_xor(s3, off, 64);
    const u64 c0 = umin64(s0, b0);
    const u64 c1 = umin64(umin64(s1, b1), umax64(s0, b0));
    const u64 c2 = umin64(umin64(s2, b2),
                          umin64(umax64(s1, b0), umax64(s0, b1)));
    const u64 c3 = umin64(umin64(umin64(s3, b3), umax64(s2, b0)),
                          umin64(umax64(s0, b2), umax64(s1, b1)));
    s0 = c0; s1 = c1; s2 = c2; s3 = c3;
  }
  const u64 sel[4] = {s0, s1, s2, s3};

  // ---- phase 2: fp64 rescore, lane handles channels c = j*16 + l15
  float zq[16];
#pragma unroll
  for (int j = 0; j < 16; ++j) zq[j] = zs[hwl][j * 16 + l15];

  double bd = 1e300;
  int bi = 0x7fffffff;
  float keep[16];
#pragma unroll
  for (int j = 0; j < 16; ++j) keep[j] = 0.f;
#pragma unroll
  for (int c4 = 0; c4 < 4; ++c4) {
    const int idx = (int)(unsigned)(sel[c4] & 0xffffffffull);
    const float* er = emb + (size_t)idx * CD;
    float ev[16];
#pragma unroll
    for (int j = 0; j < 16; ++j) ev[j] = er[j * 16 + l15];
    double s = 0.0;
#pragma unroll
    for (int j = 0; j < 16; ++j) {
      const double d = (double)zq[j] - (double)ev[j];
      s += d * d;
    }
#pragma unroll
    for (int off = 1; off < 16; off <<= 1) s += __shfl_xor(s, off, 64);
    const bool better = (s < bd) || (s == bd && idx < bi);  // uniform in 16-lane group
    if (better) {
      bd = s; bi = idx;
#pragma unroll
      for (int j = 0; j < 16; ++j) keep[j] = ev[j];
    }
  }
  // ---- phase 3: winner row -> tile, transpose-store to out
#pragma unroll
  for (int j = 0; j < 16; ++j) tile[hwl][j * 16 + l15] = keep[j];
  __syncthreads();
  const int cluster = t >> 4;   // 0..15
  const int ll      = t & 15;
  float* obase = out + (size_t)b * CD * HW + hw0 + ll;
#pragma unroll
  for (int j = 0; j < 16; ++j) {
    const int c = 16 * j + cluster;
    obase[(size_t)c * HW] = tile[ll][c];
  }
}

extern "C" void kernel_launch(void* const* d_in, const int* in_sizes, int n_in,
                              void* d_out, int out_size, void* d_ws, size_t ws_size,
                              hipStream_t stream) {
  const float* z   = (const float*)d_in[0];
  const float* emb = (const float*)d_in[1];
  float* out = (float*)d_out;

  char* ws = (char*)d_ws;
  u16*   zTb  = (u16*)(ws + ZTB_OFF);
  u16*   embB = (u16*)(ws + EMBB_OFF);
  float* eH   = (float*)(ws + EH_OFF);
  u64*   cand = (u64*)(ws + CAND_OFF);

  k_prep<<<1280, 256, 0, stream>>>(z, emb, zTb, embB, eH);
  k_argmin<<<1024, 256, 0, stream>>>(zTb, embB, eH, cand);
  k_pick_out<<<1024, 256, 0, stream>>>(z, emb, cand, out);
}